// Round 1
// baseline (1754.615 us; speedup 1.0000x reference)
//
#include <hip/hip_runtime.h>
#include <math.h>

#define SCALE_ 0.125f

// ---------- transpose x [B,D,M,N] -> xt [B,N,M,D] ----------
__global__ __launch_bounds__(256) void k_transpose(const float* __restrict__ x, float* __restrict__ xt) {
  __shared__ float tile[32][33];
  int bm = blockIdx.z; int b = bm >> 3; int m = bm & 7;
  int d0 = blockIdx.x * 32, n0 = blockIdx.y * 32;
#pragma unroll
  for (int r = 0; r < 32; r += 8) {
    int d = d0 + threadIdx.y + r, n = n0 + threadIdx.x;
    tile[threadIdx.y + r][threadIdx.x] = x[((size_t)(b * 256 + d) * 8 + m) * 256 + n];
  }
  __syncthreads();
#pragma unroll
  for (int r = 0; r < 32; r += 8) {
    int n = n0 + threadIdx.y + r, d = d0 + threadIdx.x;
    xt[((size_t)(b * 256 + n) * 8 + m) * 256 + d] = tile[threadIdx.x][threadIdx.y + r];
  }
}

// ---------- generic fp32 GEMM: C[M,N] = A[M,K] @ B[K,N] (+bias per col) ----------
// 64x64 tile, BK=16, 256 threads, 4x4 per thread. M%64==0, N%64==0, K%16==0.
__global__ __launch_bounds__(256) void k_gemm(const float* __restrict__ A, const float* __restrict__ Bm,
                                              const float* __restrict__ bias, float* __restrict__ C,
                                              int M, int N, int K) {
  __shared__ float As[16][68];
  __shared__ float Bs[16][68];
  int tid = threadIdx.x;
  int row0 = blockIdx.y * 64, col0 = blockIdx.x * 64;
  int tx = tid & 15, ty = tid >> 4;
  int lr = tid >> 2, lc = (tid & 3) * 4;
  int br = tid >> 4, bc = (tid & 15) * 4;
  float acc[4][4] = {};
  for (int k0 = 0; k0 < K; k0 += 16) {
    float4 a4 = *(const float4*)&A[(size_t)(row0 + lr) * K + k0 + lc];
    float4 b4 = *(const float4*)&Bm[(size_t)(k0 + br) * N + col0 + bc];
    As[lc + 0][lr] = a4.x; As[lc + 1][lr] = a4.y; As[lc + 2][lr] = a4.z; As[lc + 3][lr] = a4.w;
    *(float4*)&Bs[br][bc] = b4;
    __syncthreads();
#pragma unroll
    for (int kk = 0; kk < 16; kk++) {
      float4 av = *(const float4*)&As[kk][ty * 4];
      float4 bv = *(const float4*)&Bs[kk][tx * 4];
      float a[4] = {av.x, av.y, av.z, av.w};
      float b[4] = {bv.x, bv.y, bv.z, bv.w};
#pragma unroll
      for (int i = 0; i < 4; i++)
#pragma unroll
        for (int jj = 0; jj < 4; jj++)
          acc[i][jj] = fmaf(a[i], b[jj], acc[i][jj]);
    }
    __syncthreads();
  }
#pragma unroll
  for (int i = 0; i < 4; i++) {
    int r = row0 + ty * 4 + i;
#pragma unroll
    for (int jj = 0; jj < 4; jj++) {
      int c = col0 + tx * 4 + jj;
      float vb = bias ? bias[c] : 0.0f;
      C[(size_t)r * N + c] = acc[i][jj] + vb;
    }
  }
}

// ---------- attention pass 1: rden[b,h,j,m,z] = 1 / sum_i exp(q[b,i,m,h,:]·k[b,j,z,h,:]*SCALE) ----------
// block = (b, h, j-group of 4); thread t = i (0..255)
__global__ __launch_bounds__(256) void k_attn_den(const float* __restrict__ qbuf, const float* __restrict__ kvbuf,
                                                  float* __restrict__ rdg) {
  __shared__ float ks[4 * 8 * 68];
  __shared__ float red[1024];
  int idx = blockIdx.x;
  int j4 = idx & 63, h = (idx >> 6) & 7, b = idx >> 9;
  int t = threadIdx.x;
  int lane = t & 63, w = t >> 6;
#pragma unroll
  for (int rep = 0; rep < 8; rep++) {
    int e = rep * 256 + t;
    int jj = e >> 9, zz = (e >> 6) & 7, dd = e & 63;
    ks[(jj * 8 + zz) * 68 + dd] = kvbuf[((size_t)((b * 256 + j4 * 4 + jj) * 8 + zz)) * 1024 + h * 64 + dd];
  }
  __syncthreads();
  for (int m = 0; m < 8; m++) {
    const float4* qp = (const float4*)&qbuf[((size_t)((b * 256 + t) * 8 + m)) * 512 + h * 64];
    float4 qr[16];
#pragma unroll
    for (int d4 = 0; d4 < 16; d4++) qr[d4] = qp[d4];
    for (int jj = 0; jj < 4; jj++) {
#pragma unroll
      for (int z = 0; z < 8; z++) {
        const float4* kp = (const float4*)&ks[(jj * 8 + z) * 68];
        float dot = 0.0f;
#pragma unroll
        for (int d4 = 0; d4 < 16; d4++) {
          float4 kk = kp[d4];
          dot = fmaf(qr[d4].x, kk.x, dot); dot = fmaf(qr[d4].y, kk.y, dot);
          dot = fmaf(qr[d4].z, kk.z, dot); dot = fmaf(qr[d4].w, kk.w, dot);
        }
        float e = __expf(dot * SCALE_);
        e += __shfl_xor(e, 1); e += __shfl_xor(e, 2); e += __shfl_xor(e, 4);
        e += __shfl_xor(e, 8); e += __shfl_xor(e, 16); e += __shfl_xor(e, 32);
        if (lane == 0) red[w * 256 + jj * 64 + m * 8 + z] = e;
      }
    }
  }
  __syncthreads();
  {
    float den = red[t] + red[256 + t] + red[512 + t] + red[768 + t];
    int jj = t >> 6, mz = t & 63;
    rdg[((size_t)((b * 8 + h) * 256 + j4 * 4 + jj)) * 64 + mz] = 1.0f / den;
  }
}

// ---------- attention pass 2: out[b,i,z,h,d] = sum_{j,m} exp(S)*rden * v[b,j,m,h,d] ----------
// block = (b, h, i-group of 4); wave w handles i = i0+w; lane = d; p computed per lane=(m*8+z)
__global__ __launch_bounds__(256) void k_attn_out(const float* __restrict__ qbuf, const float* __restrict__ kvbuf,
                                                  const float* __restrict__ rdg, float* __restrict__ obuf) {
  __shared__ float qs[4 * 8 * 68];
  __shared__ float ks[8 * 68];
  __shared__ float vs[8 * 68];
  int idx = blockIdx.x;
  int i4 = idx & 63, h = (idx >> 6) & 7, b = idx >> 9;
  int t = threadIdx.x;
  int lane = t & 63, w = t >> 6;
  int i = i4 * 4 + w;
#pragma unroll
  for (int m = 0; m < 8; m++)
    qs[(w * 8 + m) * 68 + lane] = qbuf[((size_t)((b * 256 + i) * 8 + m)) * 512 + h * 64 + lane];
  int mm = lane >> 3, zz = lane & 7;
  float acc[8] = {0, 0, 0, 0, 0, 0, 0, 0};
  for (int j = 0; j < 256; j++) {
    __syncthreads();
    {
      int e = t; int zr = e >> 6; int dd = e & 63;
      size_t kb = ((size_t)((b * 256 + j) * 8 + zr)) * 1024 + h * 64 + dd;
      ks[zr * 68 + dd] = kvbuf[kb];
      vs[zr * 68 + dd] = kvbuf[kb + 512];
      e = t + 256; zr = e >> 6; dd = e & 63;
      kb = ((size_t)((b * 256 + j) * 8 + zr)) * 1024 + h * 64 + dd;
      ks[zr * 68 + dd] = kvbuf[kb];
      vs[zr * 68 + dd] = kvbuf[kb + 512];
    }
    float rdv = rdg[((size_t)((b * 8 + h) * 256 + j)) * 64 + lane];
    __syncthreads();
    const float4* qp = (const float4*)&qs[(w * 8 + mm) * 68];
    const float4* kp = (const float4*)&ks[zz * 68];
    float dot = 0.0f;
#pragma unroll
    for (int d4 = 0; d4 < 16; d4++) {
      float4 qa = qp[d4]; float4 kb4 = kp[d4];
      dot = fmaf(qa.x, kb4.x, dot); dot = fmaf(qa.y, kb4.y, dot);
      dot = fmaf(qa.z, kb4.z, dot); dot = fmaf(qa.w, kb4.w, dot);
    }
    float p = __expf(dot * SCALE_) * rdv;
    float vv[8];
#pragma unroll
    for (int m2 = 0; m2 < 8; m2++) vv[m2] = vs[m2 * 68 + lane];
#pragma unroll
    for (int z2 = 0; z2 < 8; z2++)
#pragma unroll
      for (int m2 = 0; m2 < 8; m2++)
        acc[z2] = fmaf(__shfl(p, m2 * 8 + z2, 64), vv[m2], acc[z2]);
  }
#pragma unroll
  for (int z2 = 0; z2 < 8; z2++)
    obuf[((size_t)((b * 256 + i) * 8 + z2)) * 512 + h * 64 + lane] = acc[z2];
}

// ---------- fused residual + layernorm over last dim (256) ----------
__global__ __launch_bounds__(256) void k_ln(const float* __restrict__ X, const float* __restrict__ R,
                                            const float* __restrict__ g, const float* __restrict__ be,
                                            float* __restrict__ Y) {
  __shared__ float sm[8];
  int row = blockIdx.x, t = threadIdx.x;
  int lane = t & 63, w = t >> 6;
  size_t base = (size_t)row * 256;
  float v = X[base + t] + R[base + t];
  float s = v;
  s += __shfl_xor(s, 1); s += __shfl_xor(s, 2); s += __shfl_xor(s, 4);
  s += __shfl_xor(s, 8); s += __shfl_xor(s, 16); s += __shfl_xor(s, 32);
  if (lane == 0) sm[w] = s;
  __syncthreads();
  float mu = (sm[0] + sm[1] + sm[2] + sm[3]) * (1.0f / 256.0f);
  float dv = v - mu;
  float s2 = dv * dv;
  s2 += __shfl_xor(s2, 1); s2 += __shfl_xor(s2, 2); s2 += __shfl_xor(s2, 4);
  s2 += __shfl_xor(s2, 8); s2 += __shfl_xor(s2, 16); s2 += __shfl_xor(s2, 32);
  if (lane == 0) sm[4 + w] = s2;
  __syncthreads();
  float var = (sm[4] + sm[5] + sm[6] + sm[7]) * (1.0f / 256.0f);
  float rs = rsqrtf(var + 1e-5f);
  Y[base + t] = dv * rs * g[t] + be[t];
}

// ---------- GEGLU: gg[r,c] = hg[r,c] * gelu(hg[r,1024+c]), exact erf gelu ----------
__global__ __launch_bounds__(256) void k_geglu(const float* __restrict__ hg, float* __restrict__ gg) {
  int idx = blockIdx.x * 256 + threadIdx.x;
  int r = idx >> 10, c = idx & 1023;
  float a = hg[(size_t)r * 2048 + c];
  float gt = hg[(size_t)r * 2048 + 1024 + c];
  float ge = 0.5f * gt * (1.0f + erff(gt * 0.70710678118654752f));
  gg[idx] = a * ge;
}

extern "C" void kernel_launch(void* const* d_in, const int* in_sizes, int n_in,
                              void* d_out, int out_size, void* d_ws, size_t ws_size,
                              hipStream_t stream) {
  const float* x    = (const float*)d_in[0];
  const float* Wq   = (const float*)d_in[1];
  const float* Wkv  = (const float*)d_in[2];
  const float* Wout = (const float*)d_in[3];
  const float* bout = (const float*)d_in[4];
  const float* g1   = (const float*)d_in[5];
  const float* be1  = (const float*)d_in[6];
  const float* Wff1 = (const float*)d_in[7];
  const float* bff1 = (const float*)d_in[8];
  const float* Wff2 = (const float*)d_in[9];
  const float* bff2 = (const float*)d_in[10];
  const float* g2   = (const float*)d_in[11];
  const float* be2  = (const float*)d_in[12];
  float* out = (float*)d_out;
  float* w = (float*)d_ws;

  // workspace layout (floats); hg aliases the dead q|kv|ao region after attention
  float* xt  = w;             // 1,048,576   [B,N,M,D]
  float* q   = w + 1048576;   // 2,097,152   [4096, 512]
  float* kv  = w + 3145728;   // 4,194,304   [4096, 1024] (k | v)
  float* ao  = w + 7340032;   // 2,097,152   [512, 4096]  attn out
  float* hg  = q;             // 8,388,608   [4096, 2048] aliases q..ao
  float* rdg = w + 9437184;   //   262,144   1/den  [b,h,j,m,z]
  float* o   = w + 9699328;   // 1,048,576   [512, 2048] == [B,N,M,D]
  float* y   = w + 10747904;  // 1,048,576   after LN1
  float* gg  = w + 11796480;  // 4,194,304   [4096, 1024]
  float* ff  = w + 15990784;  // 1,048,576   [4096, 256]

  k_transpose<<<dim3(8, 8, 16), dim3(32, 8), 0, stream>>>(x, xt);
  k_gemm<<<dim3(8, 64), 256, 0, stream>>>(xt, Wq, nullptr, q, 4096, 512, 256);
  k_gemm<<<dim3(16, 64), 256, 0, stream>>>(xt, Wkv, nullptr, kv, 4096, 1024, 256);
  k_attn_den<<<1024, 256, 0, stream>>>(q, kv, rdg);
  k_attn_out<<<1024, 256, 0, stream>>>(q, kv, rdg, ao);
  k_gemm<<<dim3(32, 8), 256, 0, stream>>>(ao, Wout, bout, o, 512, 2048, 4096);
  k_ln<<<4096, 256, 0, stream>>>(xt, o, g1, be1, y);
  k_gemm<<<dim3(32, 64), 256, 0, stream>>>(y, Wff1, bff1, hg, 4096, 2048, 256);
  k_geglu<<<16384, 256, 0, stream>>>(hg, gg);
  k_gemm<<<dim3(4, 64), 256, 0, stream>>>(gg, Wff2, bff2, ff, 4096, 256, 1024);
  k_ln<<<4096, 256, 0, stream>>>(y, ff, g2, be2, out);
}

// Round 2
// 659.788 us; speedup vs baseline: 2.6594x; 2.6594x over previous
//
#include <hip/hip_runtime.h>
#include <math.h>

#define SCALE_ 0.125f

typedef __attribute__((ext_vector_type(8))) short bf16x8;
typedef __attribute__((ext_vector_type(4))) float f32x4;

__device__ inline short f2bf(float f) {
  unsigned u = __builtin_bit_cast(unsigned, f);
  u += 0x7fff + ((u >> 16) & 1);
  return (short)(u >> 16);
}

// ---------- transpose x [B,D,M,N] -> xt [B,N,M,D] ----------
__global__ __launch_bounds__(256) void k_transpose(const float* __restrict__ x, float* __restrict__ xt) {
  __shared__ float tile[32][33];
  int bm = blockIdx.z; int b = bm >> 3; int m = bm & 7;
  int d0 = blockIdx.x * 32, n0 = blockIdx.y * 32;
#pragma unroll
  for (int r = 0; r < 32; r += 8) {
    int d = d0 + threadIdx.y + r, n = n0 + threadIdx.x;
    tile[threadIdx.y + r][threadIdx.x] = x[((size_t)(b * 256 + d) * 8 + m) * 256 + n];
  }
  __syncthreads();
#pragma unroll
  for (int r = 0; r < 32; r += 8) {
    int n = n0 + threadIdx.y + r, d = d0 + threadIdx.x;
    xt[((size_t)(b * 256 + n) * 8 + m) * 256 + d] = tile[threadIdx.x][threadIdx.y + r];
  }
}

// ---------- generic fp32 GEMM: C[M,N] = A[M,K] @ B[K,N] (+bias per col) ----------
__global__ __launch_bounds__(256) void k_gemm(const float* __restrict__ A, const float* __restrict__ Bm,
                                              const float* __restrict__ bias, float* __restrict__ C,
                                              int M, int N, int K) {
  __shared__ float As[16][68];
  __shared__ float Bs[16][68];
  int tid = threadIdx.x;
  int row0 = blockIdx.y * 64, col0 = blockIdx.x * 64;
  int tx = tid & 15, ty = tid >> 4;
  int lr = tid >> 2, lc = (tid & 3) * 4;
  int br = tid >> 4, bc = (tid & 15) * 4;
  float acc[4][4] = {};
  for (int k0 = 0; k0 < K; k0 += 16) {
    float4 a4 = *(const float4*)&A[(size_t)(row0 + lr) * K + k0 + lc];
    float4 b4 = *(const float4*)&Bm[(size_t)(k0 + br) * N + col0 + bc];
    As[lc + 0][lr] = a4.x; As[lc + 1][lr] = a4.y; As[lc + 2][lr] = a4.z; As[lc + 3][lr] = a4.w;
    *(float4*)&Bs[br][bc] = b4;
    __syncthreads();
#pragma unroll
    for (int kk = 0; kk < 16; kk++) {
      float4 av = *(const float4*)&As[kk][ty * 4];
      float4 bv = *(const float4*)&Bs[kk][tx * 4];
      float a[4] = {av.x, av.y, av.z, av.w};
      float b[4] = {bv.x, bv.y, bv.z, bv.w};
#pragma unroll
      for (int i = 0; i < 4; i++)
#pragma unroll
        for (int jj = 0; jj < 4; jj++)
          acc[i][jj] = fmaf(a[i], b[jj], acc[i][jj]);
    }
    __syncthreads();
  }
#pragma unroll
  for (int i = 0; i < 4; i++) {
    int r = row0 + ty * 4 + i;
#pragma unroll
    for (int jj = 0; jj < 4; jj++) {
      int c = col0 + tx * 4 + jj;
      float vb = bias ? bias[c] : 0.0f;
      C[(size_t)r * N + c] = acc[i][jj] + vb;
    }
  }
}

// ---------- prep: q fp32 [4096,512] -> q_bf[bh][i*8+m][d] bf16 ----------
__global__ __launch_bounds__(256) void k_prep_q(const float* __restrict__ q, short* __restrict__ qbf) {
  int c = blockIdx.x * 256 + threadIdx.x;   // 262144 threads
  int dc = c & 7, h = (c >> 3) & 7, row = c >> 6;   // row = (b*256+i)*8+m
  int b = row >> 11;
  const float* src = q + (size_t)row * 512 + h * 64 + dc * 8;
  float4 f0 = *(const float4*)src, f1 = *(const float4*)(src + 4);
  bf16x8 o;
  o[0] = f2bf(f0.x); o[1] = f2bf(f0.y); o[2] = f2bf(f0.z); o[3] = f2bf(f0.w);
  o[4] = f2bf(f1.x); o[5] = f2bf(f1.y); o[6] = f2bf(f1.z); o[7] = f2bf(f1.w);
  *(bf16x8*)(qbf + (size_t)((b * 8 + h) * 2048 + (row & 2047)) * 64 + dc * 8) = o;
}

// ---------- prep: kv k-part -> k_bf[bh][j*8+z][d] bf16 ----------
__global__ __launch_bounds__(256) void k_prep_k(const float* __restrict__ kv, short* __restrict__ kbf) {
  int c = blockIdx.x * 256 + threadIdx.x;
  int dc = c & 7, h = (c >> 3) & 7, row = c >> 6;   // row = (b*256+j)*8+z
  int b = row >> 11;
  const float* src = kv + (size_t)row * 1024 + h * 64 + dc * 8;
  float4 f0 = *(const float4*)src, f1 = *(const float4*)(src + 4);
  bf16x8 o;
  o[0] = f2bf(f0.x); o[1] = f2bf(f0.y); o[2] = f2bf(f0.z); o[3] = f2bf(f0.w);
  o[4] = f2bf(f1.x); o[5] = f2bf(f1.y); o[6] = f2bf(f1.z); o[7] = f2bf(f1.w);
  *(bf16x8*)(kbf + (size_t)((b * 8 + h) * 2048 + (row & 2047)) * 64 + dc * 8) = o;
}

// ---------- prep: kv v-part -> vT[bh][d][m*256+j] bf16 (transposed) ----------
__global__ __launch_bounds__(256) void k_prep_v(const float* __restrict__ kv, short* __restrict__ vT) {
  __shared__ float ld[64][68];
  int jt = blockIdx.x, m = blockIdx.y, bh = blockIdx.z;
  int b = bh >> 3, h = bh & 7;
  int t = threadIdx.x;
  int jr = t >> 2, c4 = t & 3;
  const float* src = kv + (size_t)((b * 256 + jt * 64 + jr) * 8 + m) * 1024 + 512 + h * 64;
#pragma unroll
  for (int r = 0; r < 4; r++) {
    float4 f = *(const float4*)(src + (c4 + r * 4) * 4);
    *(float4*)&ld[jr][(c4 + r * 4) * 4] = f;
  }
  __syncthreads();
  int d = t >> 2, jg = (t & 3) * 16;
  short* dst = vT + (size_t)(bh * 64 + d) * 2048 + m * 256 + jt * 64 + jg;
  bf16x8 o0, o1;
#pragma unroll
  for (int jj = 0; jj < 8; jj++) o0[jj] = f2bf(ld[jg + jj][d]);
#pragma unroll
  for (int jj = 0; jj < 8; jj++) o1[jj] = f2bf(ld[jg + 8 + jj][d]);
  *(bf16x8*)dst = o0;
  *(bf16x8*)(dst + 8) = o1;
}

// ---------- attention pass 1 (MFMA): rdg[bh][col=(j*8+z)][m] = 1/sum_i exp(S*scale) ----------
// block: (ct,bh); 128 cols per block; wave owns 2 colfrags; loops all 128 row-steps
__global__ __launch_bounds__(256) void k_attn_den(const short* __restrict__ qbf, const short* __restrict__ kbf,
                                                  float* __restrict__ rdg) {
  int ct = blockIdx.x, bh = blockIdx.y;
  int t = threadIdx.x;
  int w = t >> 6, lane = t & 63, quad = lane >> 4, l16 = lane & 15;
  const short* qb = qbf + (size_t)bh * 131072;
  const short* kb = kbf + (size_t)bh * 131072;
  bf16x8 bfr[2][2];
  int colb[2];
#pragma unroll
  for (int cfi = 0; cfi < 2; cfi++) {
    int col = ct * 128 + (2 * w + cfi) * 16 + l16;
    colb[cfi] = col;
#pragma unroll
    for (int ks = 0; ks < 2; ks++)
      bfr[cfi][ks] = *(const bf16x8*)(kb + col * 64 + ks * 32 + quad * 8);
  }
  f32x4 dacc0 = {0, 0, 0, 0}, dacc1 = {0, 0, 0, 0};
  bf16x8 a0 = *(const bf16x8*)(qb + l16 * 64 + quad * 8);
  bf16x8 a1 = *(const bf16x8*)(qb + l16 * 64 + 32 + quad * 8);
  for (int rs = 0; rs < 128; rs++) {
    bf16x8 na0 = a0, na1 = a1;
    if (rs < 127) {
      na0 = *(const bf16x8*)(qb + ((rs + 1) * 16 + l16) * 64 + quad * 8);
      na1 = *(const bf16x8*)(qb + ((rs + 1) * 16 + l16) * 64 + 32 + quad * 8);
    }
    f32x4 c0 = {0, 0, 0, 0}, c1 = {0, 0, 0, 0};
    c0 = __builtin_amdgcn_mfma_f32_16x16x32_bf16(a0, bfr[0][0], c0, 0, 0, 0);
    c0 = __builtin_amdgcn_mfma_f32_16x16x32_bf16(a1, bfr[0][1], c0, 0, 0, 0);
    c1 = __builtin_amdgcn_mfma_f32_16x16x32_bf16(a0, bfr[1][0], c1, 0, 0, 0);
    c1 = __builtin_amdgcn_mfma_f32_16x16x32_bf16(a1, bfr[1][1], c1, 0, 0, 0);
#pragma unroll
    for (int r = 0; r < 4; r++) {
      dacc0[r] += __expf(c0[r] * SCALE_);
      dacc1[r] += __expf(c1[r] * SCALE_);
    }
    a0 = na0; a1 = na1;
  }
#pragma unroll
  for (int r = 0; r < 4; r++) {
    float t0 = dacc0[r] + __shfl_xor(dacc0[r], 32);
    float t1 = dacc1[r] + __shfl_xor(dacc1[r], 32);
    if (quad < 2) {
      int m = quad * 4 + r;
      rdg[(size_t)(bh * 2048 + colb[0]) * 8 + m] = 1.0f / t0;
      rdg[(size_t)(bh * 2048 + colb[1]) * 8 + m] = 1.0f / t1;
    }
  }
}

// ---------- attention pass 2 (MFMA): out[i,z,h,d] ----------
// block: (it, z, bh); i-tile 16 (128 S-rows), j-loop in tiles of 32; S recomputed, P via LDS
__global__ __launch_bounds__(256) void k_attn_out(const short* __restrict__ qbf, const short* __restrict__ kbf,
                                                  const short* __restrict__ vT, const float* __restrict__ rdg,
                                                  float* __restrict__ ao) {
  __shared__ short P[16 * 264];
  __shared__ float rds[256];
  int it = blockIdx.x, z = blockIdx.y, bh = blockIdx.z;
  int b = bh >> 3, h = bh & 7;
  int t = threadIdx.x, w = t >> 6, lane = t & 63, quad = lane >> 4, l16 = lane & 15;
  const short* qb = qbf + (size_t)bh * 131072;
  const short* kb = kbf + (size_t)bh * 131072;
  const short* vb = vT + (size_t)bh * 131072;
  bf16x8 afr[2][2];
#pragma unroll
  for (int rf = 0; rf < 2; rf++)
#pragma unroll
    for (int ks = 0; ks < 2; ks++)
      afr[rf][ks] = *(const bf16x8*)(qb + (it * 128 + (w * 2 + rf) * 16 + l16) * 64 + ks * 32 + quad * 8);
  f32x4 acc = {0, 0, 0, 0};
  for (int jt = 0; jt < 8; jt++) {
    {
      int jj = t >> 3, m = t & 7;
      rds[jj * 8 + m] = rdg[(size_t)(bh * 2048 + (jt * 32 + jj) * 8 + z) * 8 + m];
    }
    __syncthreads();
    f32x4 c00 = {0,0,0,0}, c01 = {0,0,0,0}, c10 = {0,0,0,0}, c11 = {0,0,0,0};
#pragma unroll
    for (int ks = 0; ks < 2; ks++) {
      bf16x8 bf0 = *(const bf16x8*)(kb + ((jt * 32 + l16) * 8 + z) * 64 + ks * 32 + quad * 8);
      bf16x8 bf1 = *(const bf16x8*)(kb + ((jt * 32 + 16 + l16) * 8 + z) * 64 + ks * 32 + quad * 8);
      c00 = __builtin_amdgcn_mfma_f32_16x16x32_bf16(afr[0][ks], bf0, c00, 0, 0, 0);
      c01 = __builtin_amdgcn_mfma_f32_16x16x32_bf16(afr[0][ks], bf1, c01, 0, 0, 0);
      c10 = __builtin_amdgcn_mfma_f32_16x16x32_bf16(afr[1][ks], bf0, c10, 0, 0, 0);
      c11 = __builtin_amdgcn_mfma_f32_16x16x32_bf16(afr[1][ks], bf1, c11, 0, 0, 0);
    }
#pragma unroll
    for (int rf = 0; rf < 2; rf++)
#pragma unroll
      for (int cf = 0; cf < 2; cf++) {
        f32x4 cc = rf == 0 ? (cf == 0 ? c00 : c01) : (cf == 0 ? c10 : c11);
#pragma unroll
        for (int r = 0; r < 4; r++) {
          int row = (w * 2 + rf) * 16 + quad * 4 + r;
          int il = row >> 3, m = row & 7;
          int jl = cf * 16 + l16;
          float pn = __expf(cc[r] * SCALE_) * rds[jl * 8 + m];
          P[il * 264 + m * 32 + jl] = f2bf(pn);
        }
      }
    __syncthreads();
#pragma unroll
    for (int ks2 = 0; ks2 < 8; ks2++) {
      bf16x8 ap = *(const bf16x8*)(&P[l16 * 264 + ks2 * 32 + quad * 8]);
      bf16x8 bp = *(const bf16x8*)(vb + (w * 16 + l16) * 2048 + ks2 * 256 + jt * 32 + quad * 8);
      acc = __builtin_amdgcn_mfma_f32_16x16x32_bf16(ap, bp, acc, 0, 0, 0);
    }
    __syncthreads();
  }
#pragma unroll
  for (int r = 0; r < 4; r++) {
    int i = it * 16 + quad * 4 + r;
    ao[(size_t)((b * 256 + i) * 8 + z) * 512 + h * 64 + w * 16 + l16] = acc[r];
  }
}

// ---------- fused residual + layernorm over last dim (256) ----------
__global__ __launch_bounds__(256) void k_ln(const float* __restrict__ X, const float* __restrict__ R,
                                            const float* __restrict__ g, const float* __restrict__ be,
                                            float* __restrict__ Y) {
  __shared__ float sm[8];
  int row = blockIdx.x, t = threadIdx.x;
  int lane = t & 63, w = t >> 6;
  size_t base = (size_t)row * 256;
  float v = X[base + t] + R[base + t];
  float s = v;
  s += __shfl_xor(s, 1); s += __shfl_xor(s, 2); s += __shfl_xor(s, 4);
  s += __shfl_xor(s, 8); s += __shfl_xor(s, 16); s += __shfl_xor(s, 32);
  if (lane == 0) sm[w] = s;
  __syncthreads();
  float mu = (sm[0] + sm[1] + sm[2] + sm[3]) * (1.0f / 256.0f);
  float dv = v - mu;
  float s2 = dv * dv;
  s2 += __shfl_xor(s2, 1); s2 += __shfl_xor(s2, 2); s2 += __shfl_xor(s2, 4);
  s2 += __shfl_xor(s2, 8); s2 += __shfl_xor(s2, 16); s2 += __shfl_xor(s2, 32);
  if (lane == 0) sm[4 + w] = s2;
  __syncthreads();
  float var = (sm[4] + sm[5] + sm[6] + sm[7]) * (1.0f / 256.0f);
  float rs = rsqrtf(var + 1e-5f);
  Y[base + t] = dv * rs * g[t] + be[t];
}

// ---------- GEGLU ----------
__global__ __launch_bounds__(256) void k_geglu(const float* __restrict__ hg, float* __restrict__ gg) {
  int idx = blockIdx.x * 256 + threadIdx.x;
  int r = idx >> 10, c = idx & 1023;
  float a = hg[(size_t)r * 2048 + c];
  float gt = hg[(size_t)r * 2048 + 1024 + c];
  float ge = 0.5f * gt * (1.0f + erff(gt * 0.70710678118654752f));
  gg[idx] = a * ge;
}

extern "C" void kernel_launch(void* const* d_in, const int* in_sizes, int n_in,
                              void* d_out, int out_size, void* d_ws, size_t ws_size,
                              hipStream_t stream) {
  const float* x    = (const float*)d_in[0];
  const float* Wq   = (const float*)d_in[1];
  const float* Wkv  = (const float*)d_in[2];
  const float* Wout = (const float*)d_in[3];
  const float* bout = (const float*)d_in[4];
  const float* g1   = (const float*)d_in[5];
  const float* be1  = (const float*)d_in[6];
  const float* Wff1 = (const float*)d_in[7];
  const float* bff1 = (const float*)d_in[8];
  const float* Wff2 = (const float*)d_in[9];
  const float* bff2 = (const float*)d_in[10];
  const float* g2   = (const float*)d_in[11];
  const float* be2  = (const float*)d_in[12];
  float* out = (float*)d_out;
  float* w = (float*)d_ws;

  float* xt  = w;             // 1,048,576
  float* q   = w + 1048576;   // 2,097,152  [4096,512]
  float* kv  = w + 3145728;   // 4,194,304  [4096,1024]
  float* ao  = w + 7340032;   // 2,097,152  [512,4096]
  float* hg  = q;             // aliases q..ao (dead after attention)
  float* rdg = w + 9437184;   //   262,144  [bh][2048][8]
  float* o   = w + 9699328;   // 1,048,576
  float* y   = w + 10747904;  // 1,048,576
  float* gg  = w + 11796480;  // 4,194,304 (holds bf16 bufs during attention; geglu output later)
  float* ff  = w + 15990784;  // 1,048,576
  short* qbf = (short*)(w + 11796480);  // 2,097,152 shorts  [bh][2048][64]
  short* kbf = (short*)(w + 12845056);  // 2,097,152 shorts
  short* vTb = (short*)(w + 13893632);  // 2,097,152 shorts  [bh][64][2048]

  k_transpose<<<dim3(8, 8, 16), dim3(32, 8), 0, stream>>>(x, xt);
  k_gemm<<<dim3(8, 64), 256, 0, stream>>>(xt, Wq, nullptr, q, 4096, 512, 256);
  k_gemm<<<dim3(16, 64), 256, 0, stream>>>(xt, Wkv, nullptr, kv, 4096, 1024, 256);
  k_prep_q<<<1024, 256, 0, stream>>>(q, qbf);
  k_prep_k<<<1024, 256, 0, stream>>>(kv, kbf);
  k_prep_v<<<dim3(4, 8, 16), 256, 0, stream>>>(kv, vTb);
  k_attn_den<<<dim3(16, 16), 256, 0, stream>>>(qbf, kbf, rdg);
  k_attn_out<<<dim3(16, 8, 16), 256, 0, stream>>>(qbf, kbf, vTb, rdg, ao);
  k_gemm<<<dim3(32, 8), 256, 0, stream>>>(ao, Wout, bout, o, 512, 2048, 4096);
  k_ln<<<4096, 256, 0, stream>>>(xt, o, g1, be1, y);
  k_gemm<<<dim3(32, 64), 256, 0, stream>>>(y, Wff1, bff1, hg, 4096, 2048, 256);
  k_geglu<<<16384, 256, 0, stream>>>(hg, gg);
  k_gemm<<<dim3(4, 64), 256, 0, stream>>>(gg, Wff2, bff2, ff, 4096, 256, 1024);
  k_ln<<<4096, 256, 0, stream>>>(y, ff, g2, be2, out);
}

// Round 3
// 379.660 us; speedup vs baseline: 4.6215x; 1.7378x over previous
//
#include <hip/hip_runtime.h>
#include <math.h>

#define SCALE_ 0.125f

typedef __attribute__((ext_vector_type(8))) short bf16x8;
typedef __attribute__((ext_vector_type(4))) float f32x4;

__device__ inline short f2bf(float f) {
  unsigned u = __builtin_bit_cast(unsigned, f);
  u += 0x7fff + ((u >> 16) & 1);
  return (short)(u >> 16);
}

// ---------- transpose x [B,D,M,N] -> xt [B,N,M,D] fp32 + bf16 ----------
__global__ __launch_bounds__(256) void k_transpose(const float* __restrict__ x, float* __restrict__ xt,
                                                   short* __restrict__ xtbf) {
  __shared__ float tile[32][33];
  int bm = blockIdx.z; int b = bm >> 3; int m = bm & 7;
  int d0 = blockIdx.x * 32, n0 = blockIdx.y * 32;
#pragma unroll
  for (int r = 0; r < 32; r += 8) {
    int d = d0 + threadIdx.y + r, n = n0 + threadIdx.x;
    tile[threadIdx.y + r][threadIdx.x] = x[((size_t)(b * 256 + d) * 8 + m) * 256 + n];
  }
  __syncthreads();
#pragma unroll
  for (int r = 0; r < 32; r += 8) {
    int n = n0 + threadIdx.y + r, d = d0 + threadIdx.x;
    float v = tile[threadIdx.x][threadIdx.y + r];
    size_t idx = ((size_t)(b * 256 + n) * 8 + m) * 256 + d;
    xt[idx] = v;
    xtbf[idx] = f2bf(v);
  }
}

// ---------- weight transpose+convert: W fp32 [K][N] -> WT bf16 [N][K] ----------
__global__ __launch_bounds__(256) void k_wt(const float* __restrict__ W, short* __restrict__ WT, int K, int N) {
  __shared__ float tile[32][33];
  int n0 = blockIdx.x * 32, k0 = blockIdx.y * 32;
  int tx = threadIdx.x & 31, ty = threadIdx.x >> 5;
#pragma unroll
  for (int r = 0; r < 32; r += 8)
    tile[ty + r][tx] = W[(size_t)(k0 + ty + r) * N + n0 + tx];
  __syncthreads();
#pragma unroll
  for (int r = 0; r < 32; r += 8)
    WT[(size_t)(n0 + ty + r) * K + k0 + tx] = f2bf(tile[tx][ty + r]);
}

// ---------- bf16 MFMA GEMM: C[M,N] = A[M,K](bf16 rowmajor) @ BT[N,K](bf16) + bias ----------
// 64x64 tile, BK=32, 4 waves in 2x2, each wave 32x32 (2x2 fragments of 16x16x32)
__global__ __launch_bounds__(256) void k_gemm_bf(const short* __restrict__ A, const short* __restrict__ Bt,
                                                 const float* __restrict__ bias, float* __restrict__ C,
                                                 int M, int N, int K) {
  __shared__ short As[64 * 40];
  __shared__ short Bs[64 * 40];
  int t = threadIdx.x;
  int row0 = blockIdx.y * 64, col0 = blockIdx.x * 64;
  int w = t >> 6, lane = t & 63, quad = lane >> 4, l16 = lane & 15;
  int wr = w >> 1, wc = w & 1;
  int lrow = t >> 2, lch = (t & 3) * 8;
  f32x4 acc[2][2] = {{{0,0,0,0},{0,0,0,0}},{{0,0,0,0},{0,0,0,0}}};
  for (int k0 = 0; k0 < K; k0 += 32) {
    bf16x8 av = *(const bf16x8*)(A + (size_t)(row0 + lrow) * K + k0 + lch);
    bf16x8 bv = *(const bf16x8*)(Bt + (size_t)(col0 + lrow) * K + k0 + lch);
    *(bf16x8*)&As[lrow * 40 + lch] = av;
    *(bf16x8*)&Bs[lrow * 40 + lch] = bv;
    __syncthreads();
    bf16x8 af[2], bf[2];
#pragma unroll
    for (int rf = 0; rf < 2; rf++) af[rf] = *(const bf16x8*)&As[(wr * 32 + rf * 16 + l16) * 40 + quad * 8];
#pragma unroll
    for (int cf = 0; cf < 2; cf++) bf[cf] = *(const bf16x8*)&Bs[(wc * 32 + cf * 16 + l16) * 40 + quad * 8];
#pragma unroll
    for (int rf = 0; rf < 2; rf++)
#pragma unroll
      for (int cf = 0; cf < 2; cf++)
        acc[rf][cf] = __builtin_amdgcn_mfma_f32_16x16x32_bf16(af[rf], bf[cf], acc[rf][cf], 0, 0, 0);
    __syncthreads();
  }
#pragma unroll
  for (int rf = 0; rf < 2; rf++)
#pragma unroll
    for (int cf = 0; cf < 2; cf++) {
      int col = col0 + wc * 32 + cf * 16 + l16;
      float vb = bias ? bias[col] : 0.0f;
#pragma unroll
      for (int r = 0; r < 4; r++) {
        int row = row0 + wr * 32 + rf * 16 + quad * 4 + r;
        C[(size_t)row * N + col] = acc[rf][cf][r] + vb;
      }
    }
}

// ---------- prep: q fp32 [4096,512] -> q_bf[bh][i*8+m][d] bf16 ----------
__global__ __launch_bounds__(256) void k_prep_q(const float* __restrict__ q, short* __restrict__ qbf) {
  int c = blockIdx.x * 256 + threadIdx.x;
  int dc = c & 7, h = (c >> 3) & 7, row = c >> 6;
  int b = row >> 11;
  const float* src = q + (size_t)row * 512 + h * 64 + dc * 8;
  float4 f0 = *(const float4*)src, f1 = *(const float4*)(src + 4);
  bf16x8 o;
  o[0] = f2bf(f0.x); o[1] = f2bf(f0.y); o[2] = f2bf(f0.z); o[3] = f2bf(f0.w);
  o[4] = f2bf(f1.x); o[5] = f2bf(f1.y); o[6] = f2bf(f1.z); o[7] = f2bf(f1.w);
  *(bf16x8*)(qbf + (size_t)((b * 8 + h) * 2048 + (row & 2047)) * 64 + dc * 8) = o;
}

// ---------- prep: kv k-part -> k_bf[bh][j*8+z][d] bf16 ----------
__global__ __launch_bounds__(256) void k_prep_k(const float* __restrict__ kv, short* __restrict__ kbf) {
  int c = blockIdx.x * 256 + threadIdx.x;
  int dc = c & 7, h = (c >> 3) & 7, row = c >> 6;
  int b = row >> 11;
  const float* src = kv + (size_t)row * 1024 + h * 64 + dc * 8;
  float4 f0 = *(const float4*)src, f1 = *(const float4*)(src + 4);
  bf16x8 o;
  o[0] = f2bf(f0.x); o[1] = f2bf(f0.y); o[2] = f2bf(f0.z); o[3] = f2bf(f0.w);
  o[4] = f2bf(f1.x); o[5] = f2bf(f1.y); o[6] = f2bf(f1.z); o[7] = f2bf(f1.w);
  *(bf16x8*)(kbf + (size_t)((b * 8 + h) * 2048 + (row & 2047)) * 64 + dc * 8) = o;
}

// ---------- prep: kv v-part -> vT[bh][d][m*256+j] bf16 (transposed) ----------
__global__ __launch_bounds__(256) void k_prep_v(const float* __restrict__ kv, short* __restrict__ vT) {
  __shared__ float ld[64][68];
  int jt = blockIdx.x, m = blockIdx.y, bh = blockIdx.z;
  int b = bh >> 3, h = bh & 7;
  int t = threadIdx.x;
  int jr = t >> 2, c4 = t & 3;
  const float* src = kv + (size_t)((b * 256 + jt * 64 + jr) * 8 + m) * 1024 + 512 + h * 64;
#pragma unroll
  for (int r = 0; r < 4; r++) {
    float4 f = *(const float4*)(src + (c4 + r * 4) * 4);
    *(float4*)&ld[jr][(c4 + r * 4) * 4] = f;
  }
  __syncthreads();
  int d = t >> 2, jg = (t & 3) * 16;
  short* dst = vT + (size_t)(bh * 64 + d) * 2048 + m * 256 + jt * 64 + jg;
  bf16x8 o0, o1;
#pragma unroll
  for (int jj = 0; jj < 8; jj++) o0[jj] = f2bf(ld[jg + jj][d]);
#pragma unroll
  for (int jj = 0; jj < 8; jj++) o1[jj] = f2bf(ld[jg + 8 + jj][d]);
  *(bf16x8*)dst = o0;
  *(bf16x8*)(dst + 8) = o1;
}

// ---------- attention pass 1 (MFMA): rdg[bh][col=(j*8+z)][m] = 1/sum_i exp(S*scale) ----------
__global__ __launch_bounds__(256) void k_attn_den(const short* __restrict__ qbf, const short* __restrict__ kbf,
                                                  float* __restrict__ rdg) {
  int ct = blockIdx.x, bh = blockIdx.y;
  int t = threadIdx.x;
  int w = t >> 6, lane = t & 63, quad = lane >> 4, l16 = lane & 15;
  const short* qb = qbf + (size_t)bh * 131072;
  const short* kb = kbf + (size_t)bh * 131072;
  bf16x8 bfr[2][2];
  int colb[2];
#pragma unroll
  for (int cfi = 0; cfi < 2; cfi++) {
    int col = ct * 128 + (2 * w + cfi) * 16 + l16;
    colb[cfi] = col;
#pragma unroll
    for (int ks = 0; ks < 2; ks++)
      bfr[cfi][ks] = *(const bf16x8*)(kb + col * 64 + ks * 32 + quad * 8);
  }
  f32x4 dacc0 = {0, 0, 0, 0}, dacc1 = {0, 0, 0, 0};
  bf16x8 a0 = *(const bf16x8*)(qb + l16 * 64 + quad * 8);
  bf16x8 a1 = *(const bf16x8*)(qb + l16 * 64 + 32 + quad * 8);
  for (int rs = 0; rs < 128; rs++) {
    bf16x8 na0 = a0, na1 = a1;
    if (rs < 127) {
      na0 = *(const bf16x8*)(qb + ((rs + 1) * 16 + l16) * 64 + quad * 8);
      na1 = *(const bf16x8*)(qb + ((rs + 1) * 16 + l16) * 64 + 32 + quad * 8);
    }
    f32x4 c0 = {0, 0, 0, 0}, c1 = {0, 0, 0, 0};
    c0 = __builtin_amdgcn_mfma_f32_16x16x32_bf16(a0, bfr[0][0], c0, 0, 0, 0);
    c0 = __builtin_amdgcn_mfma_f32_16x16x32_bf16(a1, bfr[0][1], c0, 0, 0, 0);
    c1 = __builtin_amdgcn_mfma_f32_16x16x32_bf16(a0, bfr[1][0], c1, 0, 0, 0);
    c1 = __builtin_amdgcn_mfma_f32_16x16x32_bf16(a1, bfr[1][1], c1, 0, 0, 0);
#pragma unroll
    for (int r = 0; r < 4; r++) {
      dacc0[r] += __expf(c0[r] * SCALE_);
      dacc1[r] += __expf(c1[r] * SCALE_);
    }
    a0 = na0; a1 = na1;
  }
#pragma unroll
  for (int r = 0; r < 4; r++) {
    float t0 = dacc0[r] + __shfl_xor(dacc0[r], 32);
    float t1 = dacc1[r] + __shfl_xor(dacc1[r], 32);
    if (quad < 2) {
      int m = quad * 4 + r;
      rdg[(size_t)(bh * 2048 + colb[0]) * 8 + m] = 1.0f / t0;
      rdg[(size_t)(bh * 2048 + colb[1]) * 8 + m] = 1.0f / t1;
    }
  }
}

// ---------- attention pass 2 (MFMA): writes ao_bf [512 rows][4096 cols] bf16 ----------
__global__ __launch_bounds__(256) void k_attn_out(const short* __restrict__ qbf, const short* __restrict__ kbf,
                                                  const short* __restrict__ vT, const float* __restrict__ rdg,
                                                  short* __restrict__ ao) {
  __shared__ short P[16 * 264];
  __shared__ float rds[256];
  int it = blockIdx.x, z = blockIdx.y, bh = blockIdx.z;
  int b = bh >> 3, h = bh & 7;
  int t = threadIdx.x, w = t >> 6, lane = t & 63, quad = lane >> 4, l16 = lane & 15;
  const short* qb = qbf + (size_t)bh * 131072;
  const short* kb = kbf + (size_t)bh * 131072;
  const short* vb = vT + (size_t)bh * 131072;
  bf16x8 afr[2][2];
#pragma unroll
  for (int rf = 0; rf < 2; rf++)
#pragma unroll
    for (int ks = 0; ks < 2; ks++)
      afr[rf][ks] = *(const bf16x8*)(qb + (it * 128 + (w * 2 + rf) * 16 + l16) * 64 + ks * 32 + quad * 8);
  f32x4 acc = {0, 0, 0, 0};
  for (int jt = 0; jt < 8; jt++) {
    {
      int jj = t >> 3, m = t & 7;
      rds[jj * 8 + m] = rdg[(size_t)(bh * 2048 + (jt * 32 + jj) * 8 + z) * 8 + m];
    }
    __syncthreads();
    f32x4 c00 = {0,0,0,0}, c01 = {0,0,0,0}, c10 = {0,0,0,0}, c11 = {0,0,0,0};
#pragma unroll
    for (int ks = 0; ks < 2; ks++) {
      bf16x8 bf0 = *(const bf16x8*)(kb + ((jt * 32 + l16) * 8 + z) * 64 + ks * 32 + quad * 8);
      bf16x8 bf1 = *(const bf16x8*)(kb + ((jt * 32 + 16 + l16) * 8 + z) * 64 + ks * 32 + quad * 8);
      c00 = __builtin_amdgcn_mfma_f32_16x16x32_bf16(afr[0][ks], bf0, c00, 0, 0, 0);
      c01 = __builtin_amdgcn_mfma_f32_16x16x32_bf16(afr[0][ks], bf1, c01, 0, 0, 0);
      c10 = __builtin_amdgcn_mfma_f32_16x16x32_bf16(afr[1][ks], bf0, c10, 0, 0, 0);
      c11 = __builtin_amdgcn_mfma_f32_16x16x32_bf16(afr[1][ks], bf1, c11, 0, 0, 0);
    }
#pragma unroll
    for (int rf = 0; rf < 2; rf++)
#pragma unroll
      for (int cf = 0; cf < 2; cf++) {
        f32x4 cc = rf == 0 ? (cf == 0 ? c00 : c01) : (cf == 0 ? c10 : c11);
#pragma unroll
        for (int r = 0; r < 4; r++) {
          int row = (w * 2 + rf) * 16 + quad * 4 + r;
          int il = row >> 3, m = row & 7;
          int jl = cf * 16 + l16;
          float pn = __expf(cc[r] * SCALE_) * rds[jl * 8 + m];
          P[il * 264 + m * 32 + jl] = f2bf(pn);
        }
      }
    __syncthreads();
#pragma unroll
    for (int ks2 = 0; ks2 < 8; ks2++) {
      bf16x8 ap = *(const bf16x8*)(&P[l16 * 264 + ks2 * 32 + quad * 8]);
      bf16x8 bp = *(const bf16x8*)(vb + (w * 16 + l16) * 2048 + ks2 * 256 + jt * 32 + quad * 8);
      acc = __builtin_amdgcn_mfma_f32_16x16x32_bf16(ap, bp, acc, 0, 0, 0);
    }
    __syncthreads();
  }
#pragma unroll
  for (int r = 0; r < 4; r++) {
    int i = it * 16 + quad * 4 + r;
    ao[(size_t)((b * 256 + i) * 8 + z) * 512 + h * 64 + w * 16 + l16] = f2bf(acc[r]);
  }
}

// ---------- fused residual + layernorm; optional bf16 copy ----------
__global__ __launch_bounds__(256) void k_ln(const float* __restrict__ X, const float* __restrict__ R,
                                            const float* __restrict__ g, const float* __restrict__ be,
                                            float* __restrict__ Y, short* __restrict__ Ybf) {
  __shared__ float sm[8];
  int row = blockIdx.x, t = threadIdx.x;
  int lane = t & 63, w = t >> 6;
  size_t base = (size_t)row * 256;
  float v = X[base + t] + R[base + t];
  float s = v;
  s += __shfl_xor(s, 1); s += __shfl_xor(s, 2); s += __shfl_xor(s, 4);
  s += __shfl_xor(s, 8); s += __shfl_xor(s, 16); s += __shfl_xor(s, 32);
  if (lane == 0) sm[w] = s;
  __syncthreads();
  float mu = (sm[0] + sm[1] + sm[2] + sm[3]) * (1.0f / 256.0f);
  float dv = v - mu;
  float s2 = dv * dv;
  s2 += __shfl_xor(s2, 1); s2 += __shfl_xor(s2, 2); s2 += __shfl_xor(s2, 4);
  s2 += __shfl_xor(s2, 8); s2 += __shfl_xor(s2, 16); s2 += __shfl_xor(s2, 32);
  if (lane == 0) sm[4 + w] = s2;
  __syncthreads();
  float var = (sm[4] + sm[5] + sm[6] + sm[7]) * (1.0f / 256.0f);
  float rs = rsqrtf(var + 1e-5f);
  float res = dv * rs * g[t] + be[t];
  Y[base + t] = res;
  if (Ybf) Ybf[base + t] = f2bf(res);
}

// ---------- GEGLU -> bf16 ----------
__global__ __launch_bounds__(256) void k_geglu(const float* __restrict__ hg, short* __restrict__ gg) {
  int idx = blockIdx.x * 256 + threadIdx.x;
  int r = idx >> 10, c = idx & 1023;
  float a = hg[(size_t)r * 2048 + c];
  float gt = hg[(size_t)r * 2048 + 1024 + c];
  float ge = 0.5f * gt * (1.0f + erff(gt * 0.70710678118654752f));
  gg[idx] = f2bf(a * ge);
}

extern "C" void kernel_launch(void* const* d_in, const int* in_sizes, int n_in,
                              void* d_out, int out_size, void* d_ws, size_t ws_size,
                              hipStream_t stream) {
  const float* x    = (const float*)d_in[0];
  const float* Wq   = (const float*)d_in[1];
  const float* Wkv  = (const float*)d_in[2];
  const float* Wout = (const float*)d_in[3];
  const float* bout = (const float*)d_in[4];
  const float* g1   = (const float*)d_in[5];
  const float* be1  = (const float*)d_in[6];
  const float* Wff1 = (const float*)d_in[7];
  const float* bff1 = (const float*)d_in[8];
  const float* Wff2 = (const float*)d_in[9];
  const float* bff2 = (const float*)d_in[10];
  const float* g2   = (const float*)d_in[11];
  const float* be2  = (const float*)d_in[12];
  float* out = (float*)d_out;
  float* w = (float*)d_ws;

  // fp32 zone (float offsets)
  float* xt  = w;              // 1,048,576
  float* q   = w + 1048576;    // 2,097,152
  float* kv  = w + 3145728;    // 4,194,304
  float* hg  = w + 1048576;    // 8,388,608  (aliases q+kv+2M; q,kv dead before ff1)
  float* y   = w + 9437184;    // 1,048,576
  float* o   = w + 10485760;   // 1,048,576  (later reused as ff)
  float* ff  = w + 10485760;   //            (o dead after LN1)
  float* rdg = w + 11534336;   //   262,144
  // bf16 zone
  short* sb     = (short*)(w + 11796480);
  short* qbf    = sb;                    // 2,097,152
  short* kbf    = sb + 2097152;          // 2,097,152
  short* vTb    = sb + 4194304;          // 2,097,152
  short* xt_bf  = sb + 6291456;          // 1,048,576
  short* ao_bf  = sb + 7340032;          // 2,097,152
  short* y_bf   = sb + 9437184;          // 1,048,576
  short* gg_bf  = sb + 10485760;         // 4,194,304
  short* WqT    = sb + 14680064;         //   131,072
  short* WkvT   = sb + 14811136;         //   262,144
  short* WoutT  = sb + 15073280;         // 8,388,608
  short* Wff1T  = sb + 23461888;         //   524,288
  short* Wff2T  = sb + 23986176;         //   262,144

  k_transpose<<<dim3(8, 8, 16), dim3(32, 8), 0, stream>>>(x, xt, xt_bf);
  k_wt<<<dim3(16, 8), 256, 0, stream>>>(Wq, WqT, 256, 512);
  k_wt<<<dim3(32, 8), 256, 0, stream>>>(Wkv, WkvT, 256, 1024);
  k_wt<<<dim3(64, 128), 256, 0, stream>>>(Wout, WoutT, 4096, 2048);
  k_wt<<<dim3(64, 8), 256, 0, stream>>>(Wff1, Wff1T, 256, 2048);
  k_wt<<<dim3(8, 32), 256, 0, stream>>>(Wff2, Wff2T, 1024, 256);
  k_gemm_bf<<<dim3(8, 64), 256, 0, stream>>>(xt_bf, WqT, nullptr, q, 4096, 512, 256);
  k_gemm_bf<<<dim3(16, 64), 256, 0, stream>>>(xt_bf, WkvT, nullptr, kv, 4096, 1024, 256);
  k_prep_q<<<1024, 256, 0, stream>>>(q, qbf);
  k_prep_k<<<1024, 256, 0, stream>>>(kv, kbf);
  k_prep_v<<<dim3(4, 8, 16), 256, 0, stream>>>(kv, vTb);
  k_attn_den<<<dim3(16, 16), 256, 0, stream>>>(qbf, kbf, rdg);
  k_attn_out<<<dim3(16, 8, 16), 256, 0, stream>>>(qbf, kbf, vTb, rdg, ao_bf);
  k_gemm_bf<<<dim3(32, 8), 256, 0, stream>>>(ao_bf, WoutT, bout, o, 512, 2048, 4096);
  k_ln<<<4096, 256, 0, stream>>>(xt, o, g1, be1, y, y_bf);
  k_gemm_bf<<<dim3(32, 64), 256, 0, stream>>>(y_bf, Wff1T, bff1, hg, 4096, 2048, 256);
  k_geglu<<<16384, 256, 0, stream>>>(hg, gg_bf);
  k_gemm_bf<<<dim3(4, 64), 256, 0, stream>>>(gg_bf, Wff2T, bff2, ff, 4096, 256, 1024);
  k_ln<<<4096, 256, 0, stream>>>(y, ff, g2, be2, out, nullptr);
}